// Round 4
// baseline (520.607 us; speedup 1.0000x reference)
//
#include <hip/hip_runtime.h>
#include <math.h>

// GCN forward, reordered per-layer as x_{l} = relu((A x_{l-1}) @ W_l + b_l)
// (valid since A(xW) == (Ax)W). Then global max pool -> dot Wr.
//
// mm: lane = output channel; W column in 64 NAMED floats (no array -> no
// scratch); node loop is wave-uniform so x-row loads scalarize to s_load,
// inner loop is pure v_fmac_f32 with SGPR x-operand. 4 acc chains for ILP.

__global__ void init_kernel(int* counts, float* pooled, int N) {
    int i = blockIdx.x * blockDim.x + threadIdx.x;
    if (i < N) counts[i] = 0;
    if (i < 64) pooled[i] = 0.0f;  // relu >= 0 so 0-bits is max identity
}

// pass 1: reserve a slot per edge within its dst row. 800k atomics total.
__global__ void count_slot_kernel(const int* __restrict__ dst, int* counts, int* eslot, int E) {
    int e = blockIdx.x * blockDim.x + threadIdx.x;
    if (e >= E) return;
    eslot[e] = atomicAdd(&counts[dst[e]], 1);
}

// ---- two-level exclusive scan of counts -> rowptr ----
__global__ void scan1_kernel(const int* __restrict__ counts, int* bsums, int N) {
    __shared__ int s[256];
    int t = threadIdx.x, i = blockIdx.x * 256 + t;
    s[t] = (i < N) ? counts[i] : 0;
    __syncthreads();
    for (int o = 128; o > 0; o >>= 1) {
        if (t < o) s[t] += s[t + o];
        __syncthreads();
    }
    if (t == 0) bsums[blockIdx.x] = s[0];
}

__global__ void scan2_kernel(int* bsums, int nb) {  // nb <= 512
    __shared__ int s[512];
    int t = threadIdx.x;
    int v = (t < nb) ? bsums[t] : 0;
    s[t] = v; __syncthreads();
    for (int o = 1; o < 512; o <<= 1) {
        int x = (t >= o) ? s[t - o] : 0;
        __syncthreads();
        s[t] += x;
        __syncthreads();
    }
    if (t < nb) bsums[t] = s[t] - v;  // exclusive
}

__global__ void scan3_kernel(const int* __restrict__ counts, const int* __restrict__ bsums,
                             int* rowptr, int N) {
    __shared__ int s[256];
    int t = threadIdx.x, i = blockIdx.x * 256 + t;
    int v = (i < N) ? counts[i] : 0;
    s[t] = v; __syncthreads();
    for (int o = 1; o < 256; o <<= 1) {
        int x = (t >= o) ? s[t - o] : 0;
        __syncthreads();
        s[t] += x;
        __syncthreads();
    }
    if (i <= N) rowptr[i] = bsums[blockIdx.x] + s[t] - v;  // rowptr[N] == E
}

// pass 2: atomic-free CSR fill using reserved slots.
__global__ void fill2_kernel(const int* __restrict__ src, const int* __restrict__ dst,
                             const float* __restrict__ w, const int* __restrict__ rowptr,
                             const int* __restrict__ eslot, int* colsrc, float* wcsr, int E) {
    int e = blockIdx.x * blockDim.x + threadIdx.x;
    if (e >= E) return;
    int p = rowptr[dst[e]] + eslot[e];
    colsrc[p] = src[e];
    wcsr[p] = w[e];
}

// deg[i] = 1 + sum(wcsr row) (self loop), dinv = 1/sqrt(deg). Coalesced, no atomics.
__global__ void degdinv_kernel(const float* __restrict__ wcsr, const int* __restrict__ rowptr,
                               float* dinv, int N) {
    int i = blockIdx.x * blockDim.x + threadIdx.x;
    if (i >= N) return;
    float d = 1.0f;
    int jb = rowptr[i], je = rowptr[i + 1];
    for (int j = jb; j < je; ++j) d += wcsr[j];
    dinv[i] = 1.0f / sqrtf(d);
}

// in-place: wcsr[j] <- dinv[colsrc[j]] * wcsr[j] * dinv[i]
__global__ void norm_kernel(const int* __restrict__ rowptr, const int* __restrict__ colsrc,
                            const float* __restrict__ dinv, float* wcsr, int N) {
    int i = blockIdx.x * blockDim.x + threadIdx.x;
    if (i >= N) return;
    float dn = dinv[i];
    int jb = rowptr[i], je = rowptr[i + 1];
    for (int j = jb; j < je; ++j)
        wcsr[j] = dinv[colsrc[j]] * wcsr[j] * dn;
}

// 6-wide gather over raw input features: g[i] = dinv[i]^2*x[i] + sum norm*x[src].
__global__ void gather6_kernel(const float* __restrict__ x, const int* __restrict__ rowptr,
                               const int* __restrict__ colsrc, const float* __restrict__ normcsr,
                               const float* __restrict__ dinv, float* __restrict__ g, int N) {
    int i = blockIdx.x * blockDim.x + threadIdx.x;
    if (i >= N) return;
    float dn = dinv[i];
    float sc = dn * dn;
    float acc[6];
    {
        const float2* xr = (const float2*)(x + (size_t)i * 6);
        float2 a = xr[0], bv = xr[1], c = xr[2];
        acc[0] = sc * a.x; acc[1] = sc * a.y; acc[2] = sc * bv.x;
        acc[3] = sc * bv.y; acc[4] = sc * c.x; acc[5] = sc * c.y;
    }
    int jb = rowptr[i], je = rowptr[i + 1];
    for (int j = jb; j < je; ++j) {
        int s = colsrc[j];
        float nm = normcsr[j];
        const float2* xr = (const float2*)(x + (size_t)s * 6);
        float2 a = xr[0], bv = xr[1], c = xr[2];
        acc[0] = fmaf(nm, a.x, acc[0]); acc[1] = fmaf(nm, a.y, acc[1]);
        acc[2] = fmaf(nm, bv.x, acc[2]); acc[3] = fmaf(nm, bv.y, acc[3]);
        acc[4] = fmaf(nm, c.x, acc[4]); acc[5] = fmaf(nm, c.y, acc[5]);
    }
#pragma unroll
    for (int f = 0; f < 6; ++f) g[(size_t)i * 6 + f] = acc[f];
}

// 64-wide gather: wave per node, 4 edge-groups x 16 lanes, float4 per lane.
__global__ void gather64_kernel(const float* __restrict__ h, const int* __restrict__ rowptr,
                                const int* __restrict__ colsrc, const float* __restrict__ normcsr,
                                const float* __restrict__ dinv, float* __restrict__ agg, int N) {
    int wid = blockIdx.x * (blockDim.x >> 6) + (threadIdx.x >> 6);
    if (wid >= N) return;
    int lane = threadIdx.x & 63;
    int g = lane >> 4;       // edge group 0..3
    int l16 = lane & 15;     // float4 slot within row
    float4 acc = {0.f, 0.f, 0.f, 0.f};
    if (g == 0) {
        float dn = dinv[wid];
        float sc = dn * dn;
        float4 v = ((const float4*)(h + (size_t)wid * 64))[l16];
        acc.x = sc * v.x; acc.y = sc * v.y; acc.z = sc * v.z; acc.w = sc * v.w;
    }
    int jb = rowptr[wid], je = rowptr[wid + 1];
    for (int j = jb + g; j < je; j += 4) {
        int s = colsrc[j];
        float nm = normcsr[j];
        float4 v = ((const float4*)(h + (size_t)s * 64))[l16];
        acc.x = fmaf(nm, v.x, acc.x);
        acc.y = fmaf(nm, v.y, acc.y);
        acc.z = fmaf(nm, v.z, acc.z);
        acc.w = fmaf(nm, v.w, acc.w);
    }
#pragma unroll
    for (int o = 16; o <= 32; o <<= 1) {
        acc.x += __shfl_xor(acc.x, o);
        acc.y += __shfl_xor(acc.y, o);
        acc.z += __shfl_xor(acc.z, o);
        acc.w += __shfl_xor(acc.w, o);
    }
    if (g == 0) ((float4*)(agg + (size_t)wid * 64))[l16] = acc;
}

#define NPB 32  // nodes per wave

// h[n] = relu(xin[n] @ W + b), 64->64. Lane = out channel; W column held in
// 64 named VGPR floats; node loop wave-uniform -> x loads become s_load.
__global__ void __launch_bounds__(256, 4)
mm64_kernel(const float* __restrict__ xin, const float* __restrict__ W,
            const float* __restrict__ b, float* __restrict__ h, int N) {
    const int lane = threadIdx.x & 63;
    const int wv = __builtin_amdgcn_readfirstlane(threadIdx.x >> 6);
    const float vb = b[lane];
    float wc0 =W[   0+lane], wc1 =W[  64+lane], wc2 =W[ 128+lane], wc3 =W[ 192+lane];
    float wc4 =W[ 256+lane], wc5 =W[ 320+lane], wc6 =W[ 384+lane], wc7 =W[ 448+lane];
    float wc8 =W[ 512+lane], wc9 =W[ 576+lane], wc10=W[ 640+lane], wc11=W[ 704+lane];
    float wc12=W[ 768+lane], wc13=W[ 832+lane], wc14=W[ 896+lane], wc15=W[ 960+lane];
    float wc16=W[1024+lane], wc17=W[1088+lane], wc18=W[1152+lane], wc19=W[1216+lane];
    float wc20=W[1280+lane], wc21=W[1344+lane], wc22=W[1408+lane], wc23=W[1472+lane];
    float wc24=W[1536+lane], wc25=W[1600+lane], wc26=W[1664+lane], wc27=W[1728+lane];
    float wc28=W[1792+lane], wc29=W[1856+lane], wc30=W[1920+lane], wc31=W[1984+lane];
    float wc32=W[2048+lane], wc33=W[2112+lane], wc34=W[2176+lane], wc35=W[2240+lane];
    float wc36=W[2304+lane], wc37=W[2368+lane], wc38=W[2432+lane], wc39=W[2496+lane];
    float wc40=W[2560+lane], wc41=W[2624+lane], wc42=W[2688+lane], wc43=W[2752+lane];
    float wc44=W[2816+lane], wc45=W[2880+lane], wc46=W[2944+lane], wc47=W[3008+lane];
    float wc48=W[3072+lane], wc49=W[3136+lane], wc50=W[3200+lane], wc51=W[3264+lane];
    float wc52=W[3328+lane], wc53=W[3392+lane], wc54=W[3456+lane], wc55=W[3520+lane];
    float wc56=W[3584+lane], wc57=W[3648+lane], wc58=W[3712+lane], wc59=W[3776+lane];
    float wc60=W[3840+lane], wc61=W[3904+lane], wc62=W[3968+lane], wc63=W[4032+lane];

    long base = ((long)blockIdx.x * 4 + wv) * NPB;
    long rem = (long)N - base;
    int nmax = rem < NPB ? (rem < 0 ? 0 : (int)rem) : NPB;
    for (int t = 0; t < nmax; ++t) {
        const float* xr = xin + (base + t) * 64;
        float a0 = 0.f, a1 = 0.f, a2 = 0.f, a3 = 0.f;
        a0=fmaf(xr[ 0],wc0 ,a0); a1=fmaf(xr[ 1],wc1 ,a1); a2=fmaf(xr[ 2],wc2 ,a2); a3=fmaf(xr[ 3],wc3 ,a3);
        a0=fmaf(xr[ 4],wc4 ,a0); a1=fmaf(xr[ 5],wc5 ,a1); a2=fmaf(xr[ 6],wc6 ,a2); a3=fmaf(xr[ 7],wc7 ,a3);
        a0=fmaf(xr[ 8],wc8 ,a0); a1=fmaf(xr[ 9],wc9 ,a1); a2=fmaf(xr[10],wc10,a2); a3=fmaf(xr[11],wc11,a3);
        a0=fmaf(xr[12],wc12,a0); a1=fmaf(xr[13],wc13,a1); a2=fmaf(xr[14],wc14,a2); a3=fmaf(xr[15],wc15,a3);
        a0=fmaf(xr[16],wc16,a0); a1=fmaf(xr[17],wc17,a1); a2=fmaf(xr[18],wc18,a2); a3=fmaf(xr[19],wc19,a3);
        a0=fmaf(xr[20],wc20,a0); a1=fmaf(xr[21],wc21,a1); a2=fmaf(xr[22],wc22,a2); a3=fmaf(xr[23],wc23,a3);
        a0=fmaf(xr[24],wc24,a0); a1=fmaf(xr[25],wc25,a1); a2=fmaf(xr[26],wc26,a2); a3=fmaf(xr[27],wc27,a3);
        a0=fmaf(xr[28],wc28,a0); a1=fmaf(xr[29],wc29,a1); a2=fmaf(xr[30],wc30,a2); a3=fmaf(xr[31],wc31,a3);
        a0=fmaf(xr[32],wc32,a0); a1=fmaf(xr[33],wc33,a1); a2=fmaf(xr[34],wc34,a2); a3=fmaf(xr[35],wc35,a3);
        a0=fmaf(xr[36],wc36,a0); a1=fmaf(xr[37],wc37,a1); a2=fmaf(xr[38],wc38,a2); a3=fmaf(xr[39],wc39,a3);
        a0=fmaf(xr[40],wc40,a0); a1=fmaf(xr[41],wc41,a1); a2=fmaf(xr[42],wc42,a2); a3=fmaf(xr[43],wc43,a3);
        a0=fmaf(xr[44],wc44,a0); a1=fmaf(xr[45],wc45,a1); a2=fmaf(xr[46],wc46,a2); a3=fmaf(xr[47],wc47,a3);
        a0=fmaf(xr[48],wc48,a0); a1=fmaf(xr[49],wc49,a1); a2=fmaf(xr[50],wc50,a2); a3=fmaf(xr[51],wc51,a3);
        a0=fmaf(xr[52],wc52,a0); a1=fmaf(xr[53],wc53,a1); a2=fmaf(xr[54],wc54,a2); a3=fmaf(xr[55],wc55,a3);
        a0=fmaf(xr[56],wc56,a0); a1=fmaf(xr[57],wc57,a1); a2=fmaf(xr[58],wc58,a2); a3=fmaf(xr[59],wc59,a3);
        a0=fmaf(xr[60],wc60,a0); a1=fmaf(xr[61],wc61,a1); a2=fmaf(xr[62],wc62,a2); a3=fmaf(xr[63],wc63,a3);
        float r = (a0 + a1) + (a2 + a3);
        h[(base + t) * 64 + lane] = fmaxf(r + vb, 0.0f);
    }
}

// h[n] = relu(xin[n] @ W + b), 6->64. Same structure, K=6.
__global__ void __launch_bounds__(256)
mm6_kernel(const float* __restrict__ xin, const float* __restrict__ W,
           const float* __restrict__ b, float* __restrict__ h, int N) {
    const int lane = threadIdx.x & 63;
    const int wv = __builtin_amdgcn_readfirstlane(threadIdx.x >> 6);
    const float vb = b[lane];
    float wc0 = W[0 + lane], wc1 = W[64 + lane], wc2 = W[128 + lane];
    float wc3 = W[192 + lane], wc4 = W[256 + lane], wc5 = W[320 + lane];
    long base = ((long)blockIdx.x * 4 + wv) * NPB;
    long rem = (long)N - base;
    int nmax = rem < NPB ? (rem < 0 ? 0 : (int)rem) : NPB;
    for (int t = 0; t < nmax; ++t) {
        const float* xr = xin + (base + t) * 6;
        float a0 = 0.f, a1 = 0.f;
        a0 = fmaf(xr[0], wc0, a0); a1 = fmaf(xr[1], wc1, a1);
        a0 = fmaf(xr[2], wc2, a0); a1 = fmaf(xr[3], wc3, a1);
        a0 = fmaf(xr[4], wc4, a0); a1 = fmaf(xr[5], wc5, a1);
        h[(base + t) * 64 + lane] = fmaxf(a0 + a1 + vb, 0.0f);
    }
}

// pooled[f] = max_n x[n][f] via per-lane running max + one uint atomicMax (values >= 0).
__global__ void pool_kernel(const float* __restrict__ x, float* pooled, int N) {
    int lane = threadIdx.x & 63;
    int wid = blockIdx.x * (blockDim.x >> 6) + (threadIdx.x >> 6);
    int nw = gridDim.x * (blockDim.x >> 6);
    float m = 0.0f;
    for (int n = wid; n < N; n += nw)
        m = fmaxf(m, x[(size_t)n * 64 + lane]);
    atomicMax((unsigned int*)&pooled[lane], __float_as_uint(m));
}

__global__ void out_kernel(const float* __restrict__ pooled, const float* __restrict__ Wr,
                           const float* __restrict__ br, float* out) {
    int lane = threadIdx.x;
    float v = pooled[lane] * Wr[lane];
    for (int o = 32; o > 0; o >>= 1) v += __shfl_xor(v, o);
    if (lane == 0) out[0] = v + br[0];
}

extern "C" void kernel_launch(void* const* d_in, const int* in_sizes, int n_in,
                              void* d_out, int out_size, void* d_ws, size_t ws_size,
                              hipStream_t stream) {
    const float* vf = (const float*)d_in[0];
    const int* edges = (const int*)d_in[1];
    const float* w = (const float*)d_in[2];
    const float* W1 = (const float*)d_in[3];  const float* b1 = (const float*)d_in[4];
    const float* W2 = (const float*)d_in[5];  const float* b2 = (const float*)d_in[6];
    const float* W3 = (const float*)d_in[7];  const float* b3 = (const float*)d_in[8];
    const float* W4 = (const float*)d_in[9];  const float* b4 = (const float*)d_in[10];
    const float* Wr = (const float*)d_in[11]; const float* br = (const float*)d_in[12];
    float* out = (float*)d_out;

    const int FIN = 6;
    const int N = in_sizes[0] / FIN;   // 100000
    const int E = in_sizes[2];         // 800000
    const int* src = edges;
    const int* dst = edges + E;

    char* p = (char*)d_ws;
    float* dinv    = (float*)p;  p += (size_t)N * 4;
    int*   rowptr  = (int*)p;    p += (size_t)(N + 1) * 4;
    int*   counts  = (int*)p;    p += (size_t)N * 4;
    int*   eslot   = (int*)p;    p += (size_t)E * 4;
    int*   colsrc  = (int*)p;    p += (size_t)E * 4;
    float* wcsr    = (float*)p;  p += (size_t)E * 4;   // becomes normcsr in-place
    float* g6      = (float*)p;  p += (size_t)N * 6 * 4;
    float* h       = (float*)p;  p += (size_t)N * 64 * 4;
    float* agg     = (float*)p;  p += (size_t)N * 64 * 4;
    float* pooled  = (float*)p;  p += 64 * 4;
    int*   bsums   = (int*)p;    p += 512 * 4;

    const int nbN = (N + 255) / 256;          // 391
    const int nbE = (E + 255) / 256;          // 3125
    const int nbW = (N + 3) / 4;              // wave-per-node, 4 waves/block
    const int nbM = (N + 4 * NPB - 1) / (4 * NPB);  // mm blocks: 4 waves x NPB nodes

    init_kernel<<<nbN, 256, 0, stream>>>(counts, pooled, N);
    count_slot_kernel<<<nbE, 256, 0, stream>>>(dst, counts, eslot, E);
    scan1_kernel<<<nbN, 256, 0, stream>>>(counts, bsums, N);
    scan2_kernel<<<1, 512, 0, stream>>>(bsums, nbN);
    scan3_kernel<<<nbN, 256, 0, stream>>>(counts, bsums, rowptr, N);
    fill2_kernel<<<nbE, 256, 0, stream>>>(src, dst, w, rowptr, eslot, colsrc, wcsr, E);
    degdinv_kernel<<<nbN, 256, 0, stream>>>(wcsr, rowptr, dinv, N);
    norm_kernel<<<nbN, 256, 0, stream>>>(rowptr, colsrc, dinv, wcsr, N);

    // layer 1: gather 6-wide, then mm 6->64 (+bias+relu)
    gather6_kernel<<<nbN, 256, 0, stream>>>(vf, rowptr, colsrc, wcsr, dinv, g6, N);
    mm6_kernel<<<nbM, 256, 0, stream>>>(g6, W1, b1, h, N);
    // layers 2-4: gather 64-wide, then mm 64->64 (+bias+relu)
    gather64_kernel<<<nbW, 256, 0, stream>>>(h, rowptr, colsrc, wcsr, dinv, agg, N);
    mm64_kernel<<<nbM, 256, 0, stream>>>(agg, W2, b2, h, N);
    gather64_kernel<<<nbW, 256, 0, stream>>>(h, rowptr, colsrc, wcsr, dinv, agg, N);
    mm64_kernel<<<nbM, 256, 0, stream>>>(agg, W3, b3, h, N);
    gather64_kernel<<<nbW, 256, 0, stream>>>(h, rowptr, colsrc, wcsr, dinv, agg, N);
    mm64_kernel<<<nbM, 256, 0, stream>>>(agg, W4, b4, h, N);

    pool_kernel<<<256, 256, 0, stream>>>(h, pooled, N);
    out_kernel<<<1, 64, 0, stream>>>(pooled, Wr, br, out);
}

// Round 5
// 385.985 us; speedup vs baseline: 1.3488x; 1.3488x over previous
//
#include <hip/hip_runtime.h>
#include <math.h>

// GCN forward, reordered per-layer as x_{l} = relu((A x_{l-1}) @ W_l + b_l)
// (valid since A(xW) == (Ax)W). Then global max pool -> dot Wr.
//
// mm64: lane = out channel; W^T staged in LDS (padded, conflict-free b128);
// wave processes 16 nodes with acc[16] (~30 VGPRs total -> spill-proof);
// x loads are wave-uniform -> s_load into SGPRs; inner loop = v_fma w/ SGPR op.

__global__ void init_kernel(int* counts, float* pooled, int N) {
    int i = blockIdx.x * blockDim.x + threadIdx.x;
    if (i < N) counts[i] = 0;
    if (i < 64) pooled[i] = 0.0f;  // relu >= 0 so 0-bits is max identity
}

// pass 1: reserve a slot per edge within its dst row. 800k atomics total.
__global__ void count_slot_kernel(const int* __restrict__ dst, int* counts, int* eslot, int E) {
    int e = blockIdx.x * blockDim.x + threadIdx.x;
    if (e >= E) return;
    eslot[e] = atomicAdd(&counts[dst[e]], 1);
}

// ---- two-level exclusive scan of counts -> rowptr ----
__global__ void scan1_kernel(const int* __restrict__ counts, int* bsums, int N) {
    __shared__ int s[256];
    int t = threadIdx.x, i = blockIdx.x * 256 + t;
    s[t] = (i < N) ? counts[i] : 0;
    __syncthreads();
    for (int o = 128; o > 0; o >>= 1) {
        if (t < o) s[t] += s[t + o];
        __syncthreads();
    }
    if (t == 0) bsums[blockIdx.x] = s[0];
}

__global__ void scan2_kernel(int* bsums, int nb) {  // nb <= 512
    __shared__ int s[512];
    int t = threadIdx.x;
    int v = (t < nb) ? bsums[t] : 0;
    s[t] = v; __syncthreads();
    for (int o = 1; o < 512; o <<= 1) {
        int x = (t >= o) ? s[t - o] : 0;
        __syncthreads();
        s[t] += x;
        __syncthreads();
    }
    if (t < nb) bsums[t] = s[t] - v;  // exclusive
}

__global__ void scan3_kernel(const int* __restrict__ counts, const int* __restrict__ bsums,
                             int* rowptr, int N) {
    __shared__ int s[256];
    int t = threadIdx.x, i = blockIdx.x * 256 + t;
    int v = (i < N) ? counts[i] : 0;
    s[t] = v; __syncthreads();
    for (int o = 1; o < 256; o <<= 1) {
        int x = (t >= o) ? s[t - o] : 0;
        __syncthreads();
        s[t] += x;
        __syncthreads();
    }
    if (i <= N) rowptr[i] = bsums[blockIdx.x] + s[t] - v;  // rowptr[N] == E
}

// pass 2: atomic-free CSR fill using reserved slots.
__global__ void fill2_kernel(const int* __restrict__ src, const int* __restrict__ dst,
                             const float* __restrict__ w, const int* __restrict__ rowptr,
                             const int* __restrict__ eslot, int* colsrc, float* wcsr, int E) {
    int e = blockIdx.x * blockDim.x + threadIdx.x;
    if (e >= E) return;
    int p = rowptr[dst[e]] + eslot[e];
    colsrc[p] = src[e];
    wcsr[p] = w[e];
}

// deg[i] = 1 + sum(wcsr row) (self loop), dinv = 1/sqrt(deg). Coalesced, no atomics.
__global__ void degdinv_kernel(const float* __restrict__ wcsr, const int* __restrict__ rowptr,
                               float* dinv, int N) {
    int i = blockIdx.x * blockDim.x + threadIdx.x;
    if (i >= N) return;
    float d = 1.0f;
    int jb = rowptr[i], je = rowptr[i + 1];
    for (int j = jb; j < je; ++j) d += wcsr[j];
    dinv[i] = 1.0f / sqrtf(d);
}

// in-place: wcsr[j] <- dinv[colsrc[j]] * wcsr[j] * dinv[i]
__global__ void norm_kernel(const int* __restrict__ rowptr, const int* __restrict__ colsrc,
                            const float* __restrict__ dinv, float* wcsr, int N) {
    int i = blockIdx.x * blockDim.x + threadIdx.x;
    if (i >= N) return;
    float dn = dinv[i];
    int jb = rowptr[i], je = rowptr[i + 1];
    for (int j = jb; j < je; ++j)
        wcsr[j] = dinv[colsrc[j]] * wcsr[j] * dn;
}

// 6-wide gather over raw input features: g[i] = dinv[i]^2*x[i] + sum norm*x[src].
__global__ void gather6_kernel(const float* __restrict__ x, const int* __restrict__ rowptr,
                               const int* __restrict__ colsrc, const float* __restrict__ normcsr,
                               const float* __restrict__ dinv, float* __restrict__ g, int N) {
    int i = blockIdx.x * blockDim.x + threadIdx.x;
    if (i >= N) return;
    float dn = dinv[i];
    float sc = dn * dn;
    float acc[6];
    {
        const float2* xr = (const float2*)(x + (size_t)i * 6);
        float2 a = xr[0], bv = xr[1], c = xr[2];
        acc[0] = sc * a.x; acc[1] = sc * a.y; acc[2] = sc * bv.x;
        acc[3] = sc * bv.y; acc[4] = sc * c.x; acc[5] = sc * c.y;
    }
    int jb = rowptr[i], je = rowptr[i + 1];
    for (int j = jb; j < je; ++j) {
        int s = colsrc[j];
        float nm = normcsr[j];
        const float2* xr = (const float2*)(x + (size_t)s * 6);
        float2 a = xr[0], bv = xr[1], c = xr[2];
        acc[0] = fmaf(nm, a.x, acc[0]); acc[1] = fmaf(nm, a.y, acc[1]);
        acc[2] = fmaf(nm, bv.x, acc[2]); acc[3] = fmaf(nm, bv.y, acc[3]);
        acc[4] = fmaf(nm, c.x, acc[4]); acc[5] = fmaf(nm, c.y, acc[5]);
    }
#pragma unroll
    for (int f = 0; f < 6; ++f) g[(size_t)i * 6 + f] = acc[f];
}

// 64-wide gather: wave per node, 4 edge-groups x 16 lanes, float4 per lane.
__global__ void gather64_kernel(const float* __restrict__ h, const int* __restrict__ rowptr,
                                const int* __restrict__ colsrc, const float* __restrict__ normcsr,
                                const float* __restrict__ dinv, float* __restrict__ agg, int N) {
    int wid = blockIdx.x * (blockDim.x >> 6) + (threadIdx.x >> 6);
    if (wid >= N) return;
    int lane = threadIdx.x & 63;
    int g = lane >> 4;       // edge group 0..3
    int l16 = lane & 15;     // float4 slot within row
    float4 acc = {0.f, 0.f, 0.f, 0.f};
    if (g == 0) {
        float dn = dinv[wid];
        float sc = dn * dn;
        float4 v = ((const float4*)(h + (size_t)wid * 64))[l16];
        acc.x = sc * v.x; acc.y = sc * v.y; acc.z = sc * v.z; acc.w = sc * v.w;
    }
    int jb = rowptr[wid], je = rowptr[wid + 1];
    for (int j = jb + g; j < je; j += 4) {
        int s = colsrc[j];
        float nm = normcsr[j];
        float4 v = ((const float4*)(h + (size_t)s * 64))[l16];
        acc.x = fmaf(nm, v.x, acc.x);
        acc.y = fmaf(nm, v.y, acc.y);
        acc.z = fmaf(nm, v.z, acc.z);
        acc.w = fmaf(nm, v.w, acc.w);
    }
#pragma unroll
    for (int o = 16; o <= 32; o <<= 1) {
        acc.x += __shfl_xor(acc.x, o);
        acc.y += __shfl_xor(acc.y, o);
        acc.z += __shfl_xor(acc.z, o);
        acc.w += __shfl_xor(acc.w, o);
    }
    if (g == 0) ((float4*)(agg + (size_t)wid * 64))[l16] = acc;
}

#define MMNT 16  // nodes per wave-batch in mm64

// h[n] = relu(xin[n] @ W + b), 64->64.
// lane = out channel c; acc[16] nodes; W^T in LDS, 1 ds_read_b128 per 4-k chunk;
// x loads wave-uniform -> SGPRs. ~30 VGPRs -> no spill, 8 waves/SIMD.
__global__ void __launch_bounds__(256)
mm64_kernel(const float* __restrict__ xin, const float* __restrict__ W,
            const float* __restrict__ b, float* __restrict__ h, int N) {
    __shared__ float Wt[64 * 68];  // Wt[c*68 + k] = W[k*64 + c]; pad 68 -> b128 conflict-free
    for (int idx = threadIdx.x; idx < 4096; idx += 256) {
        int k = idx >> 6, c = idx & 63;
        Wt[c * 68 + k] = W[idx];
    }
    __syncthreads();
    const int lane = threadIdx.x & 63;
    const int wv = __builtin_amdgcn_readfirstlane(threadIdx.x >> 6);
    long base = ((long)blockIdx.x * 4 + wv) * MMNT;
    if (base >= N) return;
    const float vb = b[lane];
    const float* xb = xin + base * 64;

    float acc[MMNT];
#pragma unroll
    for (int t = 0; t < MMNT; ++t) acc[t] = 0.f;

#pragma unroll
    for (int kc = 0; kc < 16; ++kc) {
        float4 wr = *(const float4*)&Wt[lane * 68 + kc * 4];
#pragma unroll
        for (int t = 0; t < MMNT; ++t) {
            const float* xr = xb + t * 64 + kc * 4;   // wave-uniform -> s_load_dwordx4
            float x0 = xr[0], x1 = xr[1], x2 = xr[2], x3 = xr[3];
            acc[t] = fmaf(x3, wr.w, fmaf(x2, wr.z, fmaf(x1, wr.y, fmaf(x0, wr.x, acc[t]))));
        }
    }

#pragma unroll
    for (int t = 0; t < MMNT; ++t)
        h[(base + t) * 64 + lane] = fmaxf(acc[t] + vb, 0.0f);
}

#define NPB 32  // nodes per wave in mm6

// h[n] = relu(xin[n] @ W + b), 6->64. Tiny register footprint; x via s_load.
__global__ void __launch_bounds__(256)
mm6_kernel(const float* __restrict__ xin, const float* __restrict__ W,
           const float* __restrict__ b, float* __restrict__ h, int N) {
    const int lane = threadIdx.x & 63;
    const int wv = __builtin_amdgcn_readfirstlane(threadIdx.x >> 6);
    const float vb = b[lane];
    float wc0 = W[0 + lane], wc1 = W[64 + lane], wc2 = W[128 + lane];
    float wc3 = W[192 + lane], wc4 = W[256 + lane], wc5 = W[320 + lane];
    long base = ((long)blockIdx.x * 4 + wv) * NPB;
    long rem = (long)N - base;
    int nmax = rem < NPB ? (rem < 0 ? 0 : (int)rem) : NPB;
    for (int t = 0; t < nmax; ++t) {
        const float* xr = xin + (base + t) * 6;
        float a0 = 0.f, a1 = 0.f;
        a0 = fmaf(xr[0], wc0, a0); a1 = fmaf(xr[1], wc1, a1);
        a0 = fmaf(xr[2], wc2, a0); a1 = fmaf(xr[3], wc3, a1);
        a0 = fmaf(xr[4], wc4, a0); a1 = fmaf(xr[5], wc5, a1);
        h[(base + t) * 64 + lane] = fmaxf(a0 + a1 + vb, 0.0f);
    }
}

// pooled[f] = max_n x[n][f] via per-lane running max + one uint atomicMax (values >= 0).
__global__ void pool_kernel(const float* __restrict__ x, float* pooled, int N) {
    int lane = threadIdx.x & 63;
    int wid = blockIdx.x * (blockDim.x >> 6) + (threadIdx.x >> 6);
    int nw = gridDim.x * (blockDim.x >> 6);
    float m = 0.0f;
    for (int n = wid; n < N; n += nw)
        m = fmaxf(m, x[(size_t)n * 64 + lane]);
    atomicMax((unsigned int*)&pooled[lane], __float_as_uint(m));
}

__global__ void out_kernel(const float* __restrict__ pooled, const float* __restrict__ Wr,
                           const float* __restrict__ br, float* out) {
    int lane = threadIdx.x;
    float v = pooled[lane] * Wr[lane];
    for (int o = 32; o > 0; o >>= 1) v += __shfl_xor(v, o);
    if (lane == 0) out[0] = v + br[0];
}

extern "C" void kernel_launch(void* const* d_in, const int* in_sizes, int n_in,
                              void* d_out, int out_size, void* d_ws, size_t ws_size,
                              hipStream_t stream) {
    const float* vf = (const float*)d_in[0];
    const int* edges = (const int*)d_in[1];
    const float* w = (const float*)d_in[2];
    const float* W1 = (const float*)d_in[3];  const float* b1 = (const float*)d_in[4];
    const float* W2 = (const float*)d_in[5];  const float* b2 = (const float*)d_in[6];
    const float* W3 = (const float*)d_in[7];  const float* b3 = (const float*)d_in[8];
    const float* W4 = (const float*)d_in[9];  const float* b4 = (const float*)d_in[10];
    const float* Wr = (const float*)d_in[11]; const float* br = (const float*)d_in[12];
    float* out = (float*)d_out;

    const int FIN = 6;
    const int N = in_sizes[0] / FIN;   // 100000
    const int E = in_sizes[2];         // 800000
    const int* src = edges;
    const int* dst = edges + E;

    char* p = (char*)d_ws;
    float* dinv    = (float*)p;  p += (size_t)N * 4;
    int*   rowptr  = (int*)p;    p += (size_t)(N + 1) * 4;
    int*   counts  = (int*)p;    p += (size_t)N * 4;
    int*   eslot   = (int*)p;    p += (size_t)E * 4;
    int*   colsrc  = (int*)p;    p += (size_t)E * 4;
    float* wcsr    = (float*)p;  p += (size_t)E * 4;   // becomes normcsr in-place
    float* g6      = (float*)p;  p += (size_t)N * 6 * 4;
    float* h       = (float*)p;  p += (size_t)N * 64 * 4;
    float* agg     = (float*)p;  p += (size_t)N * 64 * 4;
    float* pooled  = (float*)p;  p += 64 * 4;
    int*   bsums   = (int*)p;    p += 512 * 4;

    const int nbN = (N + 255) / 256;          // 391
    const int nbE = (E + 255) / 256;          // 3125
    const int nbW = (N + 3) / 4;              // wave-per-node, 4 waves/block
    const int nbM = (N + 4 * MMNT - 1) / (4 * MMNT);  // mm64 blocks: 4 waves x 16 nodes
    const int nbM6 = (N + 4 * NPB - 1) / (4 * NPB);   // mm6 blocks

    init_kernel<<<nbN, 256, 0, stream>>>(counts, pooled, N);
    count_slot_kernel<<<nbE, 256, 0, stream>>>(dst, counts, eslot, E);
    scan1_kernel<<<nbN, 256, 0, stream>>>(counts, bsums, N);
    scan2_kernel<<<1, 512, 0, stream>>>(bsums, nbN);
    scan3_kernel<<<nbN, 256, 0, stream>>>(counts, bsums, rowptr, N);
    fill2_kernel<<<nbE, 256, 0, stream>>>(src, dst, w, rowptr, eslot, colsrc, wcsr, E);
    degdinv_kernel<<<nbN, 256, 0, stream>>>(wcsr, rowptr, dinv, N);
    norm_kernel<<<nbN, 256, 0, stream>>>(rowptr, colsrc, dinv, wcsr, N);

    // layer 1: gather 6-wide, then mm 6->64 (+bias+relu)
    gather6_kernel<<<nbN, 256, 0, stream>>>(vf, rowptr, colsrc, wcsr, dinv, g6, N);
    mm6_kernel<<<nbM6, 256, 0, stream>>>(g6, W1, b1, h, N);
    // layers 2-4: gather 64-wide, then mm 64->64 (+bias+relu)
    gather64_kernel<<<nbW, 256, 0, stream>>>(h, rowptr, colsrc, wcsr, dinv, agg, N);
    mm64_kernel<<<nbM, 256, 0, stream>>>(agg, W2, b2, h, N);
    gather64_kernel<<<nbW, 256, 0, stream>>>(h, rowptr, colsrc, wcsr, dinv, agg, N);
    mm64_kernel<<<nbM, 256, 0, stream>>>(agg, W3, b3, h, N);
    gather64_kernel<<<nbW, 256, 0, stream>>>(h, rowptr, colsrc, wcsr, dinv, agg, N);
    mm64_kernel<<<nbM, 256, 0, stream>>>(agg, W4, b4, h, N);

    pool_kernel<<<256, 256, 0, stream>>>(h, pooled, N);
    out_kernel<<<1, 64, 0, stream>>>(pooled, Wr, br, out);
}